// Round 4
// baseline (1893.393 us; speedup 1.0000x reference)
//
#include <hip/hip_runtime.h>

#define NB 256      // dst-range buckets
#define CHUNK 8192  // edges per partition block

// ---------------- init bucket cursors ----------------
__global__ void k_init(int* __restrict__ gcur, int capE) {
  gcur[threadIdx.x] = threadIdx.x * capE;
}

// ---------------- phase 1: partition edges into dst-range buckets ----------------
__global__ void k_part(const int* __restrict__ srcI, const int* __restrict__ dstI,
                       int* __restrict__ gcur, int2* __restrict__ pairs,
                       int E, int N, int capN, int capE) {
  __shared__ int hist[NB];
  __shared__ int base[NB];
  __shared__ int cnt[NB];
  int tid = threadIdx.x;  // 256
  int e0 = blockIdx.x * CHUNK;
  int eend = min(e0 + CHUNK, E);
  hist[tid] = 0;
  __syncthreads();
  for (int e = e0 + tid; e < eend; e += 256) {
    int d = dstI[e];
    if ((unsigned)d < (unsigned)N) atomicAdd(&hist[d / capN], 1);
  }
  __syncthreads();
  base[tid] = atomicAdd(&gcur[tid], hist[tid]);
  cnt[tid] = 0;
  __syncthreads();
  for (int e = e0 + tid; e < eend; e += 256) {
    int d = dstI[e];
    int s = srcI[e];
    if ((unsigned)d < (unsigned)N && (unsigned)s < (unsigned)N) {
      int b = d / capN;
      int slot = base[b] + atomicAdd(&cnt[b], 1);
      if (slot < (b + 1) * capE)
        pairs[slot] = make_int2(d, s);
    }
  }
}

// ---------------- phase 2: per-bucket CSR build ----------------
__launch_bounds__(512)
__global__ void k_csr(const int2* __restrict__ pairs, const int* __restrict__ gcur,
                      int* __restrict__ deg, int* __restrict__ rowoff,
                      int* __restrict__ csr, int N, int capN, int capE) {
  __shared__ int hist[512];
  __shared__ int tmp[512];
  __shared__ int cur[512];
  int q = blockIdx.x;
  int tid = threadIdx.x;
  int nloc = N - q * capN;
  if (nloc > capN) nloc = capN;
  int base = q * capE;
  int cnt = gcur[q] - base;
  if (cnt > capE) cnt = capE;
  int qbase = q * capN;
  hist[tid] = 0;
  __syncthreads();
  for (int e = tid; e < cnt; e += 512) {
    int2 pr = pairs[base + e];
    int dl = pr.x - qbase;
    if ((unsigned)dl < (unsigned)nloc && (unsigned)pr.y < (unsigned)N)
      atomicAdd(&hist[dl], 1);
  }
  __syncthreads();
  int v = hist[tid];
  tmp[tid] = v;
  __syncthreads();
  for (int off = 1; off < 512; off <<= 1) {
    int t = (tid >= off) ? tmp[tid - off] : 0;
    __syncthreads();
    tmp[tid] += t;
    __syncthreads();
  }
  int ex = tmp[tid] - v;
  cur[tid] = ex;
  if (tid < nloc) {
    int i = qbase + tid;
    deg[i] = v;
    rowoff[i] = base + ex;
  }
  __syncthreads();
  for (int e = tid; e < cnt; e += 512) {
    int2 pr = pairs[base + e];
    int dl = pr.x - qbase;
    if ((unsigned)dl < (unsigned)nloc && (unsigned)pr.y < (unsigned)N) {
      int pos = atomicAdd(&cur[dl], 1);
      csr[base + pos] = pr.y;
    }
  }
}

// ---------------- mean aggregate 64-dim: wave per node, lane per dim ----------------
__global__ void k_agg64(const float* __restrict__ x, const int* __restrict__ csr,
                        const int* __restrict__ rowoff, const int* __restrict__ deg,
                        float* __restrict__ m, int n) {
  int w = (blockIdx.x * blockDim.x + threadIdx.x) >> 6;
  int lane = threadIdx.x & 63;
  if (w >= n) return;
  int start = __builtin_amdgcn_readfirstlane(rowoff[w]);
  int d = __builtin_amdgcn_readfirstlane(deg[w]);
  float a0 = 0.f, a1 = 0.f, a2 = 0.f, a3 = 0.f;
  int j = 0;
  for (; j + 3 < d; j += 4) {
    int s0 = csr[start + j];
    int s1 = csr[start + j + 1];
    int s2 = csr[start + j + 2];
    int s3 = csr[start + j + 3];
    a0 += x[(size_t)s0 * 64 + lane];
    a1 += x[(size_t)s1 * 64 + lane];
    a2 += x[(size_t)s2 * 64 + lane];
    a3 += x[(size_t)s3 * 64 + lane];
  }
  for (; j < d; ++j) a0 += x[(size_t)csr[start + j] * 64 + lane];
  float inv = (d > 0) ? 1.f / (float)d : 0.f;
  m[(size_t)w * 64 + lane] = ((a0 + a1) + (a2 + a3)) * inv;
}

// ---------------- layer1 register-tiled GEMM: h = relu([m|x] @ [W1l;W1r] + b1) ----
// block tile: 128 rows x 64 cols; 256 thr = 32 rowT x 8 colT; thread = 4 rows x 8 cols
__launch_bounds__(256)
__global__ void k_h(const float* __restrict__ m, const float* __restrict__ x,
                    const float* __restrict__ Wl, const float* __restrict__ Wr,
                    const float* __restrict__ b1, float* __restrict__ h, int n) {
  __shared__ float sW[128 * 64];    // rows 0..63 = W1l, 64..127 = W1r (32 KB)
  __shared__ float sA[128 * 33];    // A k-tile, stride 33 to break bank strides
  int tid = threadIdx.x;
  for (int t = tid; t < 4096; t += 256) {
    sW[t] = Wl[t];
    sW[4096 + t] = Wr[t];
  }
  int row0 = blockIdx.x * 128;
  int colT = tid & 7;
  int rowT = tid >> 3;
  float acc[4][8];
#pragma unroll
  for (int r = 0; r < 4; ++r)
#pragma unroll
    for (int c = 0; c < 8; ++c) acc[r][c] = 0.f;

#pragma unroll
  for (int kt = 0; kt < 4; ++kt) {
    const float* src = (kt < 2) ? m : x;
    int ko = (kt & 1) * 32;
    __syncthreads();   // protect sA from previous iter's readers
#pragma unroll
    for (int i = 0; i < 4; ++i) {
      int t = tid + 256 * i;
      int r = t >> 3, s = t & 7;
      int rr = row0 + r; if (rr > n - 1) rr = n - 1;   // clamp: avoid OOB fault
      float4 v = *(const float4*)(src + (size_t)rr * 64 + ko + s * 4);
      float* dst = &sA[r * 33 + s * 4];
      dst[0] = v.x; dst[1] = v.y; dst[2] = v.z; dst[3] = v.w;
    }
    __syncthreads();
    int kw = kt * 32;  // weight-row offset
#pragma unroll
    for (int k = 0; k < 32; ++k) {
      float a0 = sA[(rowT * 4 + 0) * 33 + k];
      float a1 = sA[(rowT * 4 + 1) * 33 + k];
      float a2 = sA[(rowT * 4 + 2) * 33 + k];
      float a3 = sA[(rowT * 4 + 3) * 33 + k];
      const float* wrow = &sW[(kw + k) * 64 + colT * 8];
      float w0 = wrow[0], w1 = wrow[1], w2 = wrow[2], w3 = wrow[3];
      float w4 = wrow[4], w5 = wrow[5], w6 = wrow[6], w7 = wrow[7];
      acc[0][0] += a0 * w0; acc[0][1] += a0 * w1; acc[0][2] += a0 * w2; acc[0][3] += a0 * w3;
      acc[0][4] += a0 * w4; acc[0][5] += a0 * w5; acc[0][6] += a0 * w6; acc[0][7] += a0 * w7;
      acc[1][0] += a1 * w0; acc[1][1] += a1 * w1; acc[1][2] += a1 * w2; acc[1][3] += a1 * w3;
      acc[1][4] += a1 * w4; acc[1][5] += a1 * w5; acc[1][6] += a1 * w6; acc[1][7] += a1 * w7;
      acc[2][0] += a2 * w0; acc[2][1] += a2 * w1; acc[2][2] += a2 * w2; acc[2][3] += a2 * w3;
      acc[2][4] += a2 * w4; acc[2][5] += a2 * w5; acc[2][6] += a2 * w6; acc[2][7] += a2 * w7;
      acc[3][0] += a3 * w0; acc[3][1] += a3 * w1; acc[3][2] += a3 * w2; acc[3][3] += a3 * w3;
      acc[3][4] += a3 * w4; acc[3][5] += a3 * w5; acc[3][6] += a3 * w6; acc[3][7] += a3 * w7;
    }
  }
  // epilogue: bias + relu + store
  float bb[8];
#pragma unroll
  for (int c = 0; c < 8; ++c) bb[c] = b1[colT * 8 + c];
#pragma unroll
  for (int r = 0; r < 4; ++r) {
    int row = row0 + rowT * 4 + r;
    if (row < n) {
      float* dst = h + (size_t)row * 64 + colT * 8;
#pragma unroll
      for (int c = 0; c < 8; ++c) dst[c] = fmaxf(acc[r][c] + bb[c], 0.f);
    }
  }
}

// ---------------- layer2 register-tiled GEMM: p = h@W2l (ws), q = h@W2r (d_out) ----
// block tile: 128 rows x 32 cols; 256 thr = 32 rowT x 8 colT; thread = 4 rows x 4 cols
__launch_bounds__(256)
__global__ void k_pq(const float* __restrict__ h, const float* __restrict__ W2l,
                     const float* __restrict__ W2r, float* __restrict__ p,
                     float* __restrict__ q, int n) {
  __shared__ float sW[64 * 32];     // col 0..15 = W2l, 16..31 = W2r (8 KB)
  __shared__ float sA[128 * 33];
  int tid = threadIdx.x;
  for (int t = tid; t < 1024; t += 256) {
    int k = t >> 4, j = t & 15;
    sW[k * 32 + j] = W2l[t];
    sW[k * 32 + 16 + j] = W2r[t];
  }
  int row0 = blockIdx.x * 128;
  int colT = tid & 7;
  int rowT = tid >> 3;
  float acc[4][4];
#pragma unroll
  for (int r = 0; r < 4; ++r)
#pragma unroll
    for (int c = 0; c < 4; ++c) acc[r][c] = 0.f;

#pragma unroll
  for (int kt = 0; kt < 2; ++kt) {
    int ko = kt * 32;
    __syncthreads();
#pragma unroll
    for (int i = 0; i < 4; ++i) {
      int t = tid + 256 * i;
      int r = t >> 3, s = t & 7;
      int rr = row0 + r; if (rr > n - 1) rr = n - 1;
      float4 v = *(const float4*)(h + (size_t)rr * 64 + ko + s * 4);
      float* dst = &sA[r * 33 + s * 4];
      dst[0] = v.x; dst[1] = v.y; dst[2] = v.z; dst[3] = v.w;
    }
    __syncthreads();
#pragma unroll
    for (int k = 0; k < 32; ++k) {
      float a0 = sA[(rowT * 4 + 0) * 33 + k];
      float a1 = sA[(rowT * 4 + 1) * 33 + k];
      float a2 = sA[(rowT * 4 + 2) * 33 + k];
      float a3 = sA[(rowT * 4 + 3) * 33 + k];
      const float* wrow = &sW[(ko + k) * 32 + colT * 4];
      float w0 = wrow[0], w1 = wrow[1], w2 = wrow[2], w3 = wrow[3];
      acc[0][0] += a0 * w0; acc[0][1] += a0 * w1; acc[0][2] += a0 * w2; acc[0][3] += a0 * w3;
      acc[1][0] += a1 * w0; acc[1][1] += a1 * w1; acc[1][2] += a1 * w2; acc[1][3] += a1 * w3;
      acc[2][0] += a2 * w0; acc[2][1] += a2 * w1; acc[2][2] += a2 * w2; acc[2][3] += a2 * w3;
      acc[3][0] += a3 * w0; acc[3][1] += a3 * w1; acc[3][2] += a3 * w2; acc[3][3] += a3 * w3;
    }
  }
#pragma unroll
  for (int r = 0; r < 4; ++r) {
    int row = row0 + rowT * 4 + r;
    if (row < n) {
      float* dst = (colT < 4) ? (p + (size_t)row * 16 + colT * 4)
                              : (q + (size_t)row * 16 + (colT - 4) * 4);
      *(float4*)dst = make_float4(acc[r][0], acc[r][1], acc[r][2], acc[r][3]);
    }
  }
}

// ---------------- mean aggregate 16-dim + epilogue: out = mean(p_nbr) + q + b2 ----
__global__ void k_agg16(const float* __restrict__ p, const int* __restrict__ csr,
                        const int* __restrict__ rowoff, const int* __restrict__ deg,
                        const float* __restrict__ b2, float* __restrict__ out, int n) {
  int t = blockIdx.x * blockDim.x + threadIdx.x;
  int i = t >> 4;
  int dd = t & 15;
  if (i >= n) return;
  int start = rowoff[i];
  int d = deg[i];
  float a0 = 0.f, a1 = 0.f, a2 = 0.f, a3 = 0.f;
  int j = 0;
  for (; j + 3 < d; j += 4) {
    int s0 = csr[start + j];
    int s1 = csr[start + j + 1];
    int s2 = csr[start + j + 2];
    int s3 = csr[start + j + 3];
    a0 += p[(size_t)s0 * 16 + dd];
    a1 += p[(size_t)s1 * 16 + dd];
    a2 += p[(size_t)s2 * 16 + dd];
    a3 += p[(size_t)s3 * 16 + dd];
  }
  for (; j < d; ++j) a0 += p[(size_t)csr[start + j] * 16 + dd];
  float inv = (d > 0) ? 1.f / (float)d : 0.f;
  out[t] = ((a0 + a1) + (a2 + a3)) * inv + out[t] + b2[dd];
}

extern "C" void kernel_launch(void* const* d_in, const int* in_sizes, int n_in,
                              void* d_out, int out_size, void* d_ws, size_t ws_size,
                              hipStream_t stream) {
  const float* x   = (const float*)d_in[0];
  const int*   ei  = (const int*)d_in[1];
  const float* W1l = (const float*)d_in[2];
  const float* W1r = (const float*)d_in[3];
  const float* b1  = (const float*)d_in[4];
  const float* W2l = (const float*)d_in[5];
  const float* W2r = (const float*)d_in[6];
  const float* b2  = (const float*)d_in[7];
  float* out = (float*)d_out;

  int N = in_sizes[0] / 64;
  int E = in_sizes[1] / 2;
  const int* srcI = ei;
  const int* dstI = ei + E;

  int capN = (N + NB - 1) / NB;
  int capE = E / NB + 1024;

  size_t off = 0;
  auto alloc = [&](size_t bytes) -> char* {
    char* r = (char*)d_ws + off;
    off = (off + bytes + 255) & ~(size_t)255;
    return r;
  };
  int*   deg    = (int*)alloc((size_t)N * 4);
  int*   rowoff = (int*)alloc((size_t)N * 4);
  int*   csr    = (int*)alloc((size_t)NB * capE * 4);
  int*   gcur   = (int*)alloc(NB * 4);
  float* m      = (float*)alloc((size_t)N * 64 * 4);
  float* h      = (float*)alloc((size_t)N * 64 * 4);
  float* p      = (float*)alloc((size_t)N * 16 * 4);
  int2*  pairs  = (int2*)m;           // overlay: pairs dead before m is written
  if (off > ws_size) return;
  if ((size_t)NB * capE * 8 > (size_t)N * 64 * 4) return;

  int gb = (N + 127) / 128;

  k_init<<<1, NB, 0, stream>>>(gcur, capE);
  k_part<<<(E + CHUNK - 1) / CHUNK, 256, 0, stream>>>(srcI, dstI, gcur, pairs, E, N, capN, capE);
  k_csr<<<NB, 512, 0, stream>>>(pairs, gcur, deg, rowoff, csr, N, capN, capE);

  // layer 1: m = mean_agg(x); h = relu(m@W1l + x@W1r + b1)
  k_agg64<<<(N * 64 + 255) / 256, 256, 0, stream>>>(x, csr, rowoff, deg, m, N);
  k_h<<<gb, 256, 0, stream>>>(m, x, W1l, W1r, b1, h, N);

  // layer 2 (transform-first): p = h@W2l, q = h@W2r (to d_out); out = mean_agg(p)+q+b2
  k_pq<<<gb, 256, 0, stream>>>(h, W2l, W2r, p, out, N);
  k_agg16<<<(N * 16 + 255) / 256, 256, 0, stream>>>(p, csr, rowoff, deg, b2, out, N);
}

// Round 6
// 256.949 us; speedup vs baseline: 7.3687x; 7.3687x over previous
//
#include <hip/hip_runtime.h>

#define NB 256      // dst-range buckets
#define CHUNK 8192  // edges per partition block

// ---------------- init bucket cursors ----------------
__global__ void k_init(int* __restrict__ gcur, int capE) {
  gcur[threadIdx.x] = threadIdx.x * capE;
}

// ---------------- phase 1: partition edges into dst-range buckets ----------------
__global__ void k_part(const int* __restrict__ srcI, const int* __restrict__ dstI,
                       int* __restrict__ gcur, int2* __restrict__ pairs,
                       int E, int N, int capN, int capE) {
  __shared__ int hist[NB];
  __shared__ int base[NB];
  __shared__ int cnt[NB];
  int tid = threadIdx.x;  // 256
  int e0 = blockIdx.x * CHUNK;
  int eend = min(e0 + CHUNK, E);
  hist[tid] = 0;
  __syncthreads();
  for (int e = e0 + tid; e < eend; e += 256) {
    int d = dstI[e];
    if ((unsigned)d < (unsigned)N) atomicAdd(&hist[d / capN], 1);
  }
  __syncthreads();
  base[tid] = atomicAdd(&gcur[tid], hist[tid]);
  cnt[tid] = 0;
  __syncthreads();
  for (int e = e0 + tid; e < eend; e += 256) {
    int d = dstI[e];
    int s = srcI[e];
    if ((unsigned)d < (unsigned)N && (unsigned)s < (unsigned)N) {
      int b = d / capN;
      int slot = base[b] + atomicAdd(&cnt[b], 1);
      if (slot < (b + 1) * capE)
        pairs[slot] = make_int2(d, s);
    }
  }
}

// ---------------- phase 2: per-bucket CSR build ----------------
__launch_bounds__(512)
__global__ void k_csr(const int2* __restrict__ pairs, const int* __restrict__ gcur,
                      int* __restrict__ deg, int* __restrict__ rowoff,
                      int* __restrict__ csr, int N, int capN, int capE) {
  __shared__ int hist[512];
  __shared__ int tmp[512];
  __shared__ int cur[512];
  int q = blockIdx.x;
  int tid = threadIdx.x;
  int nloc = N - q * capN;
  if (nloc > capN) nloc = capN;
  int base = q * capE;
  int cnt = gcur[q] - base;
  if (cnt > capE) cnt = capE;
  int qbase = q * capN;
  hist[tid] = 0;
  __syncthreads();
  for (int e = tid; e < cnt; e += 512) {
    int2 pr = pairs[base + e];
    int dl = pr.x - qbase;
    if ((unsigned)dl < (unsigned)nloc && (unsigned)pr.y < (unsigned)N)
      atomicAdd(&hist[dl], 1);
  }
  __syncthreads();
  int v = hist[tid];
  tmp[tid] = v;
  __syncthreads();
  for (int off = 1; off < 512; off <<= 1) {
    int t = (tid >= off) ? tmp[tid - off] : 0;
    __syncthreads();
    tmp[tid] += t;
    __syncthreads();
  }
  int ex = tmp[tid] - v;
  cur[tid] = ex;
  if (tid < nloc) {
    int i = qbase + tid;
    deg[i] = v;
    rowoff[i] = base + ex;
  }
  __syncthreads();
  for (int e = tid; e < cnt; e += 512) {
    int2 pr = pairs[base + e];
    int dl = pr.x - qbase;
    if ((unsigned)dl < (unsigned)nloc && (unsigned)pr.y < (unsigned)N) {
      int pos = atomicAdd(&cur[dl], 1);
      csr[base + pos] = pr.y;
    }
  }
}

// ---------------- mean aggregate 64-dim: wave per node, lane per dim ----------------
__global__ void k_agg64(const float* __restrict__ x, const int* __restrict__ csr,
                        const int* __restrict__ rowoff, const int* __restrict__ deg,
                        float* __restrict__ m, int n) {
  int w = (blockIdx.x * blockDim.x + threadIdx.x) >> 6;
  int lane = threadIdx.x & 63;
  if (w >= n) return;
  int start = __builtin_amdgcn_readfirstlane(rowoff[w]);
  int d = __builtin_amdgcn_readfirstlane(deg[w]);
  float a0 = 0.f, a1 = 0.f, a2 = 0.f, a3 = 0.f;
  int j = 0;
  for (; j + 3 < d; j += 4) {
    int s0 = csr[start + j];
    int s1 = csr[start + j + 1];
    int s2 = csr[start + j + 2];
    int s3 = csr[start + j + 3];
    a0 += x[(size_t)s0 * 64 + lane];
    a1 += x[(size_t)s1 * 64 + lane];
    a2 += x[(size_t)s2 * 64 + lane];
    a3 += x[(size_t)s3 * 64 + lane];
  }
  for (; j < d; ++j) a0 += x[(size_t)csr[start + j] * 64 + lane];
  float inv = (d > 0) ? 1.f / (float)d : 0.f;
  m[(size_t)w * 64 + lane] = ((a0 + a1) + (a2 + a3)) * inv;
}

// ---------------- layer1 GEMM: h = relu([m|x] @ [W1l;W1r] + b1) -------------------
// tile 64 rows x 64 cols; 256 thr = 16 colT x 16 rowT; micro 4x4.
// sAT transposed [32 k][68] so 4 rows = one ds_read_b128; sW k-tile [32][64].
__launch_bounds__(256, 4)
__global__ void k_h(const float* __restrict__ m, const float* __restrict__ x,
                    const float* __restrict__ Wl, const float* __restrict__ Wr,
                    const float* __restrict__ b1, float* __restrict__ h, int n) {
  __shared__ float sAT[32 * 68];   // [k][row], stride 68 (16B-aligned, bank-spread)
  __shared__ float sW[32 * 64];    // [k][col]
  int tid = threadIdx.x;
  int row0 = blockIdx.x * 64;
  int colT = tid & 15;
  int rowT = tid >> 4;
  float acc[4][4];
#pragma unroll
  for (int r = 0; r < 4; ++r)
#pragma unroll
    for (int c = 0; c < 4; ++c) acc[r][c] = 0.f;

  for (int kt = 0; kt < 4; ++kt) {
    const float* asrc = (kt < 2) ? m : x;
    const float* wsrc = (kt < 2) ? Wl : Wr;
    int ko = (kt & 1) * 32;
    __syncthreads();  // protect LDS from previous iter's readers
    {
      // stage A-tile transposed: 64 rows x 32 k = 512 float4; 2 per thread
      int f = tid;                       // f: r=f>>3 (0..63 over 2 iters), kq=f&7
#pragma unroll
      for (int i = 0; i < 2; ++i, f += 256) {
        int r = f >> 3, kq = f & 7;
        int rr = row0 + r; if (rr > n - 1) rr = n - 1;
        float4 v = *(const float4*)(asrc + (size_t)rr * 64 + ko + kq * 4);
        sAT[(kq * 4 + 0) * 68 + r] = v.x;
        sAT[(kq * 4 + 1) * 68 + r] = v.y;
        sAT[(kq * 4 + 2) * 68 + r] = v.z;
        sAT[(kq * 4 + 3) * 68 + r] = v.w;
      }
      // stage W k-tile: 32 rows x 64 cols = 512 float4; 2 per thread
      int g = tid;                       // row=g>>4 (0..31 over 2 iters), cq=g&15
#pragma unroll
      for (int i = 0; i < 2; ++i, g += 256) {
        int wr = g >> 4, cq = g & 15;
        float4 v = *(const float4*)(wsrc + (size_t)(ko + wr) * 64 + cq * 4);
        *(float4*)&sW[wr * 64 + cq * 4] = v;
      }
    }
    __syncthreads();
#pragma unroll 4
    for (int k = 0; k < 32; ++k) {
      float4 a = *(const float4*)&sAT[k * 68 + rowT * 4];
      float4 w = *(const float4*)&sW[k * 64 + colT * 4];
      acc[0][0] += a.x * w.x; acc[0][1] += a.x * w.y; acc[0][2] += a.x * w.z; acc[0][3] += a.x * w.w;
      acc[1][0] += a.y * w.x; acc[1][1] += a.y * w.y; acc[1][2] += a.y * w.z; acc[1][3] += a.y * w.w;
      acc[2][0] += a.z * w.x; acc[2][1] += a.z * w.y; acc[2][2] += a.z * w.z; acc[2][3] += a.z * w.w;
      acc[3][0] += a.w * w.x; acc[3][1] += a.w * w.y; acc[3][2] += a.w * w.z; acc[3][3] += a.w * w.w;
    }
  }
  float4 bb = *(const float4*)(b1 + colT * 4);
#pragma unroll
  for (int r = 0; r < 4; ++r) {
    int row = row0 + rowT * 4 + r;
    if (row < n) {
      float4 o;
      o.x = fmaxf(acc[r][0] + bb.x, 0.f);
      o.y = fmaxf(acc[r][1] + bb.y, 0.f);
      o.z = fmaxf(acc[r][2] + bb.z, 0.f);
      o.w = fmaxf(acc[r][3] + bb.w, 0.f);
      *(float4*)(h + (size_t)row * 64 + colT * 4) = o;
    }
  }
}

// ---------------- layer2 GEMM: [p|q] = h @ [W2l|W2r] ------------------------------
// tile 128 rows x 32 cols; 256 thr = 8 colT x 32 rowT; micro 4x4.
__launch_bounds__(256, 4)
__global__ void k_pq(const float* __restrict__ h, const float* __restrict__ W2l,
                     const float* __restrict__ W2r, float* __restrict__ p,
                     float* __restrict__ q, int n) {
  __shared__ float sAT[32 * 132];  // [k][row], stride 132 (16B-aligned)
  __shared__ float sW[32 * 32];    // [k][col]: 0..15 = W2l row, 16..31 = W2r row
  int tid = threadIdx.x;
  int row0 = blockIdx.x * 128;
  int colT = tid & 7;
  int rowT = tid >> 3;
  float acc[4][4];
#pragma unroll
  for (int r = 0; r < 4; ++r)
#pragma unroll
    for (int c = 0; c < 4; ++c) acc[r][c] = 0.f;

  for (int kt = 0; kt < 2; ++kt) {
    int ko = kt * 32;
    __syncthreads();
    {
      // stage A-tile transposed: 128 rows x 32 k = 1024 float4; 4 per thread
      int f = tid;
#pragma unroll
      for (int i = 0; i < 4; ++i, f += 256) {
        int r = f >> 3, kq = f & 7;
        int rr = row0 + r; if (rr > n - 1) rr = n - 1;
        float4 v = *(const float4*)(h + (size_t)rr * 64 + ko + kq * 4);
        sAT[(kq * 4 + 0) * 132 + r] = v.x;
        sAT[(kq * 4 + 1) * 132 + r] = v.y;
        sAT[(kq * 4 + 2) * 132 + r] = v.z;
        sAT[(kq * 4 + 3) * 132 + r] = v.w;
      }
      // stage W k-tile: 32 k x 32 cols = 256 float4; 1 per thread
      int wr = tid >> 3, cq = tid & 7;
      const float* wsrc = (cq < 4) ? W2l : W2r;
      int cc = (cq & 3) * 4;
      float4 v = *(const float4*)(wsrc + (size_t)(ko + wr) * 16 + cc);
      *(float4*)&sW[wr * 32 + cq * 4] = v;
    }
    __syncthreads();
#pragma unroll 4
    for (int k = 0; k < 32; ++k) {
      float4 a = *(const float4*)&sAT[k * 132 + rowT * 4];
      float4 w = *(const float4*)&sW[k * 32 + colT * 4];
      acc[0][0] += a.x * w.x; acc[0][1] += a.x * w.y; acc[0][2] += a.x * w.z; acc[0][3] += a.x * w.w;
      acc[1][0] += a.y * w.x; acc[1][1] += a.y * w.y; acc[1][2] += a.y * w.z; acc[1][3] += a.y * w.w;
      acc[2][0] += a.z * w.x; acc[2][1] += a.z * w.y; acc[2][2] += a.z * w.z; acc[2][3] += a.z * w.w;
      acc[3][0] += a.w * w.x; acc[3][1] += a.w * w.y; acc[3][2] += a.w * w.z; acc[3][3] += a.w * w.w;
    }
  }
#pragma unroll
  for (int r = 0; r < 4; ++r) {
    int row = row0 + rowT * 4 + r;
    if (row < n) {
      float* dst = (colT < 4) ? (p + (size_t)row * 16 + colT * 4)
                              : (q + (size_t)row * 16 + (colT - 4) * 4);
      *(float4*)dst = make_float4(acc[r][0], acc[r][1], acc[r][2], acc[r][3]);
    }
  }
}

// ---------------- mean aggregate 16-dim + epilogue: out = mean(p_nbr) + q + b2 ----
__global__ void k_agg16(const float* __restrict__ p, const int* __restrict__ csr,
                        const int* __restrict__ rowoff, const int* __restrict__ deg,
                        const float* __restrict__ b2, float* __restrict__ out, int n) {
  int t = blockIdx.x * blockDim.x + threadIdx.x;
  int i = t >> 4;
  int dd = t & 15;
  if (i >= n) return;
  int start = rowoff[i];
  int d = deg[i];
  float a0 = 0.f, a1 = 0.f, a2 = 0.f, a3 = 0.f;
  int j = 0;
  for (; j + 3 < d; j += 4) {
    int s0 = csr[start + j];
    int s1 = csr[start + j + 1];
    int s2 = csr[start + j + 2];
    int s3 = csr[start + j + 3];
    a0 += p[(size_t)s0 * 16 + dd];
    a1 += p[(size_t)s1 * 16 + dd];
    a2 += p[(size_t)s2 * 16 + dd];
    a3 += p[(size_t)s3 * 16 + dd];
  }
  for (; j < d; ++j) a0 += p[(size_t)csr[start + j] * 16 + dd];
  float inv = (d > 0) ? 1.f / (float)d : 0.f;
  out[t] = ((a0 + a1) + (a2 + a3)) * inv + out[t] + b2[dd];
}

extern "C" void kernel_launch(void* const* d_in, const int* in_sizes, int n_in,
                              void* d_out, int out_size, void* d_ws, size_t ws_size,
                              hipStream_t stream) {
  const float* x   = (const float*)d_in[0];
  const int*   ei  = (const int*)d_in[1];
  const float* W1l = (const float*)d_in[2];
  const float* W1r = (const float*)d_in[3];
  const float* b1  = (const float*)d_in[4];
  const float* W2l = (const float*)d_in[5];
  const float* W2r = (const float*)d_in[6];
  const float* b2  = (const float*)d_in[7];
  float* out = (float*)d_out;

  int N = in_sizes[0] / 64;
  int E = in_sizes[1] / 2;
  const int* srcI = ei;
  const int* dstI = ei + E;

  int capN = (N + NB - 1) / NB;
  int capE = E / NB + 1024;

  size_t off = 0;
  auto alloc = [&](size_t bytes) -> char* {
    char* r = (char*)d_ws + off;
    off = (off + bytes + 255) & ~(size_t)255;
    return r;
  };
  int*   deg    = (int*)alloc((size_t)N * 4);
  int*   rowoff = (int*)alloc((size_t)N * 4);
  int*   csr    = (int*)alloc((size_t)NB * capE * 4);
  int*   gcur   = (int*)alloc(NB * 4);
  float* m      = (float*)alloc((size_t)N * 64 * 4);
  float* h      = (float*)alloc((size_t)N * 64 * 4);
  float* p      = (float*)alloc((size_t)N * 16 * 4);
  int2*  pairs  = (int2*)m;           // overlay: pairs dead before m is written
  if (off > ws_size) return;
  if ((size_t)NB * capE * 8 > (size_t)N * 64 * 4) return;

  k_init<<<1, NB, 0, stream>>>(gcur, capE);
  k_part<<<(E + CHUNK - 1) / CHUNK, 256, 0, stream>>>(srcI, dstI, gcur, pairs, E, N, capN, capE);
  k_csr<<<NB, 512, 0, stream>>>(pairs, gcur, deg, rowoff, csr, N, capN, capE);

  // layer 1: m = mean_agg(x); h = relu(m@W1l + x@W1r + b1)
  k_agg64<<<(N * 64 + 255) / 256, 256, 0, stream>>>(x, csr, rowoff, deg, m, N);
  k_h<<<(N + 63) / 64, 256, 0, stream>>>(m, x, W1l, W1r, b1, h, N);

  // layer 2 (transform-first): p = h@W2l, q = h@W2r (to d_out); out = mean_agg(p)+q+b2
  k_pq<<<(N + 127) / 128, 256, 0, stream>>>(h, W2l, W2r, p, out, N);
  k_agg16<<<(N * 16 + 255) / 256, 256, 0, stream>>>(p, csr, rowoff, deg, b2, out, N);
}